// Round 1
// baseline (228.597 us; speedup 1.0000x reference)
//
#include <hip/hip_runtime.h>
#include <math.h>

// Problem constants (match reference setup_inputs)
#define BB 8
#define NN 32768          // points per batch (2^15)
#define KK 16             // neighbors
#define NP (BB * NN)      // 262144 center points total
#define LL (NN * KK)      // 524288 positions per batch
#define NSTAT 35          // 7 first moments + 28 second moments (upper tri)
#define NBLK1 1024        // blocks in stats pass
#define EPSV 1e-5

// ws layout (bytes):
//   [0,           4 MiB)   xyzp  : float4[NP]   transposed coords (x,y,z,0)
//   [4 MiB, +140 KiB)      part  : float[NBLK1*NSTAT] per-block stat partials
//   [next 1 KiB)           fw    : float[32*8] folded conv+BN weights
#define XYZP_OFF 0
#define PART_OFF (NP * 16)                        // 4194304
#define FW_OFF   (PART_OFF + NBLK1 * NSTAT * 4)   // 4337664

// ---------------- Kernel 1: transpose xyz [B,3,N] -> [B*N] float4 ----------
__global__ __launch_bounds__(256) void k_transpose(const float* __restrict__ xyz,
                                                   float4* __restrict__ xyzp) {
    int t = blockIdx.x * 256 + threadIdx.x;      // t = b*N + n
    int b = t >> 15;
    int n = t & (NN - 1);
    const float* p = xyz + (size_t)b * 3 * NN + n;
    xyzp[t] = make_float4(p[0], p[NN], p[2 * NN], 0.0f);
}

// ---------------- Kernel 2: per-block moment partials ----------------------
// One thread per (b,n); loops its 16 neighbors.
// Features f = (d, c0,c1,c2, g0,g1,g2). Accumulate S1[7], S2 upper-tri[28].
__global__ __launch_bounds__(256) void k_stats(const float4* __restrict__ xyzp,
                                               const int4* __restrict__ idx4,
                                               float* __restrict__ partials) {
    int t = blockIdx.x * 256 + threadIdx.x;      // (b,n)
    int b = t >> 15;
    int pbase = b << 15;
    float4 c = xyzp[t];

    float sd = 0.f, sd2 = 0.f;
    float sg0 = 0.f, sg1 = 0.f, sg2 = 0.f;
    float sdg0 = 0.f, sdg1 = 0.f, sdg2 = 0.f;
    float s00 = 0.f, s01 = 0.f, s02 = 0.f, s11 = 0.f, s12 = 0.f, s22 = 0.f;

    const int4* ib = idx4 + (size_t)t * 4;
#pragma unroll
    for (int q = 0; q < 4; ++q) {
        int4 iv = ib[q];
        int ids[4] = {iv.x, iv.y, iv.z, iv.w};
#pragma unroll
        for (int j = 0; j < 4; ++j) {
            float4 g = xyzp[pbase + ids[j]];
            float r0 = c.x - g.x, r1 = c.y - g.y, r2 = c.z - g.z;
            float d2 = r0 * r0 + r1 * r1 + r2 * r2;
            float d  = sqrtf(d2);
            sd += d;  sd2 += d2;
            sg0 += g.x; sg1 += g.y; sg2 += g.z;
            sdg0 += d * g.x; sdg1 += d * g.y; sdg2 += d * g.z;
            s00 += g.x * g.x; s01 += g.x * g.y; s02 += g.x * g.z;
            s11 += g.y * g.y; s12 += g.y * g.z; s22 += g.z * g.z;
        }
    }

    float v[NSTAT];
    // S1 (c appears 16x per thread)
    v[0] = sd;  v[1] = 16.f * c.x; v[2] = 16.f * c.y; v[3] = 16.f * c.z;
    v[4] = sg0; v[5] = sg1; v[6] = sg2;
    // S2 upper triangle, row-major: (0,0)..(0,6),(1,1)..(1,6),...,(6,6)
    v[7]  = sd2;
    v[8]  = c.x * sd; v[9]  = c.y * sd; v[10] = c.z * sd;
    v[11] = sdg0; v[12] = sdg1; v[13] = sdg2;
    v[14] = 16.f * c.x * c.x; v[15] = 16.f * c.x * c.y; v[16] = 16.f * c.x * c.z;
    v[17] = c.x * sg0; v[18] = c.x * sg1; v[19] = c.x * sg2;
    v[20] = 16.f * c.y * c.y; v[21] = 16.f * c.y * c.z;
    v[22] = c.y * sg0; v[23] = c.y * sg1; v[24] = c.y * sg2;
    v[25] = 16.f * c.z * c.z;
    v[26] = c.z * sg0; v[27] = c.z * sg1; v[28] = c.z * sg2;
    v[29] = s00; v[30] = s01; v[31] = s02;
    v[32] = s11; v[33] = s12;
    v[34] = s22;

    // wave (64-lane) butterfly reduce each stat
#pragma unroll
    for (int j = 0; j < NSTAT; ++j) {
        float x = v[j];
#pragma unroll
        for (int m = 32; m >= 1; m >>= 1) x += __shfl_xor(x, m, 64);
        v[j] = x;
    }

    __shared__ float red[4][NSTAT];
    int wave = threadIdx.x >> 6;
    int lane = threadIdx.x & 63;
    if (lane == 0) {
#pragma unroll
        for (int j = 0; j < NSTAT; ++j) red[wave][j] = v[j];
    }
    __syncthreads();
    if (threadIdx.x < NSTAT) {
        int j = threadIdx.x;
        partials[(size_t)blockIdx.x * NSTAT + j] =
            red[0][j] + red[1][j] + red[2][j] + red[3][j];
    }
}

// ---------------- Kernel 3: finalize stats, fold BN into conv --------------
// Block dim (35, 8). Double-precision reduction of 1024 partials, then 32
// threads compute per-channel mean/var and the folded weights:
//   fw[o*8 + {0..6}] = M*s, fw[o*8+7] = (b - mean_h)*s + beta,
// where M = (A, U, V), s = gamma/sqrt(var+eps).
__global__ void k_finalize(const float* __restrict__ partials,
                           const float* __restrict__ W,
                           const float* __restrict__ bias,
                           const float* __restrict__ gamma,
                           const float* __restrict__ beta,
                           float* __restrict__ fw) {
    __shared__ double part[8][NSTAT];
    __shared__ double st[NSTAT];
    int j  = threadIdx.x;   // 0..34
    int cy = threadIdx.y;   // 0..7
    double s = 0.0;
    for (int i = cy * 128; i < (cy + 1) * 128; ++i)
        s += (double)partials[(size_t)i * NSTAT + j];
    part[cy][j] = s;
    __syncthreads();
    if (cy == 0) {
        double tot = 0.0;
        for (int y = 0; y < 8; ++y) tot += part[y][j];
        st[j] = tot;
    }
    __syncthreads();

    int tid = cy * 35 + j;
    if (tid < 32) {
        int o = tid;
        double M[7];
        M[0] = (double)W[o * 10 + 0];                                 // dist
        for (int x = 0; x < 3; ++x) {
            M[1 + x] = (double)W[o * 10 + 1 + x] + (double)W[o * 10 + 4 + x]; // center
            M[4 + x] = (double)W[o * 10 + 7 + x] - (double)W[o * 10 + 1 + x]; // neighbor
        }
        const double inv = 1.0 / ((double)BB * (double)LL);
        double mf[7];
        for (int i = 0; i < 7; ++i) mf[i] = st[i] * inv;
        double mh = (double)bias[o];
        for (int i = 0; i < 7; ++i) mh += M[i] * mf[i];
        double var = 0.0;
        for (int i = 0; i < 7; ++i)
            for (int k = 0; k < 7; ++k) {
                int a = i < k ? i : k;
                int b2 = i < k ? k : i;
                int u = 7 + 7 * a - (a * (a - 1)) / 2 + (b2 - a);
                double cov = st[u] * inv - mf[i] * mf[k];
                var += M[i] * M[k] * cov;
            }
        double sc = (double)gamma[o] / sqrt(var + EPSV);
        for (int x = 0; x < 7; ++x) fw[o * 8 + x] = (float)(M[x] * sc);
        fw[o * 8 + 7] = (float)(((double)bias[o] - mh) * sc + (double)beta[o]);
    }
}

// ---------------- Kernel 4: apply folded conv+BN+LeakyReLU, write out ------
// One thread per 4 positions. Lane l: n = base+(l>>2), k-quad = l&3, so for
// each o the wave's float4 stores are byte-contiguous (1 KB/instr) and the
// int4 idx loads are perfectly coalesced.
__global__ __launch_bounds__(256) void k_apply(const float4* __restrict__ xyzp,
                                               const int4* __restrict__ idx4,
                                               const float* __restrict__ fw,
                                               float* __restrict__ out) {
    int t  = blockIdx.x * 256 + threadIdx.x;   // [0, NP*4)
    int ng = t >> 2;                           // global point index b*N+n
    int b  = ng >> 15;
    int nb = ng & (NN - 1);
    int kq = t & 3;

    float4 c  = xyzp[ng];
    int4   iv = idx4[t];                       // idx4[(b*N+n)*4 + kq] == idx4[t]
    int pbase = b << 15;
    int ids[4] = {iv.x, iv.y, iv.z, iv.w};

    float d[4], gx[4], gy[4], gz[4];
#pragma unroll
    for (int j = 0; j < 4; ++j) {
        float4 g = xyzp[pbase + ids[j]];
        float r0 = c.x - g.x, r1 = c.y - g.y, r2 = c.z - g.z;
        d[j]  = sqrtf(r0 * r0 + r1 * r1 + r2 * r2);
        gx[j] = g.x; gy[j] = g.y; gz[j] = g.z;
    }

    const float4* fw4 = (const float4*)fw;
    float* op = out + (size_t)b * 32 * LL + (size_t)nb * 16 + kq * 4;
#pragma unroll 8
    for (int o = 0; o < 32; ++o) {
        float4 wA = fw4[o * 2];       // {A, U0, U1, U2}
        float4 wB = fw4[o * 2 + 1];   // {V0, V1, V2, Fb}
        float hc = wB.w + wA.y * c.x + wA.z * c.y + wA.w * c.z;
        float4 r;
        {
            float h = hc + wA.x * d[0] + wB.x * gx[0] + wB.y * gy[0] + wB.z * gz[0];
            r.x = fmaxf(h, 0.01f * h);
        }
        {
            float h = hc + wA.x * d[1] + wB.x * gx[1] + wB.y * gy[1] + wB.z * gz[1];
            r.y = fmaxf(h, 0.01f * h);
        }
        {
            float h = hc + wA.x * d[2] + wB.x * gx[2] + wB.y * gy[2] + wB.z * gz[2];
            r.z = fmaxf(h, 0.01f * h);
        }
        {
            float h = hc + wA.x * d[3] + wB.x * gx[3] + wB.y * gy[3] + wB.z * gz[3];
            r.w = fmaxf(h, 0.01f * h);
        }
        *(float4*)(op + (size_t)o * LL) = r;
    }
}

extern "C" void kernel_launch(void* const* d_in, const int* in_sizes, int n_in,
                              void* d_out, int out_size, void* d_ws, size_t ws_size,
                              hipStream_t stream) {
    const float* xyz   = (const float*)d_in[0];   // [B,3,N] f32
    const int*   nidx  = (const int*)d_in[1];     // [B,N,K] int32
    const float* W     = (const float*)d_in[2];   // [32,10]
    const float* bias  = (const float*)d_in[3];   // [32]
    const float* gamma = (const float*)d_in[4];   // [32]
    const float* beta  = (const float*)d_in[5];   // [32]
    float*       out   = (float*)d_out;

    char* ws = (char*)d_ws;
    float4* xyzp    = (float4*)(ws + XYZP_OFF);
    float*  partial = (float*)(ws + PART_OFF);
    float*  fw      = (float*)(ws + FW_OFF);
    const int4* idx4 = (const int4*)nidx;

    k_transpose<<<NP / 256, 256, 0, stream>>>(xyz, xyzp);
    k_stats<<<NBLK1, 256, 0, stream>>>(xyzp, idx4, partial);
    k_finalize<<<1, dim3(35, 8), 0, stream>>>(partial, W, bias, gamma, beta, fw);
    k_apply<<<(NP * 4) / 256, 256, 0, stream>>>(xyzp, idx4, fw, out);
}